// Round 1
// baseline (505.020 us; speedup 1.0000x reference)
//
#include <hip/hip_runtime.h>

#define FDIM 2668

typedef float f32x4 __attribute__((ext_vector_type(4)));
typedef _Float16 f16x8 __attribute__((ext_vector_type(8)));

// ---- packed-B geometry (all element counts in f16 halfwords) ----
// G1: userid  K=960  (30 ksteps), N=144 (9 tiles):  [uu 0:64 | ui 64:128 | lin n=128 | pad]
// G2: itemid  K=1696 (53 ksteps), N=144 (9 tiles):  base col 940 (3 dummy cols for alignment)
// G3: smalls  K=64   (2 ksteps),  N=464 (29 tiles): [P|Q0|mu|mi|au|gu|ou| lin n=448 |pad]
#define G1_NK 30
#define G2_NK 53
#define G3_NK 2
#define G1_NT 9
#define G2_NT 9
#define G3_NT 29
#define BUF_BYTES (G3_NT * 1024)   // 29696 B: per-kstep LDS buffer (max over phases)

#define HU 0
#define HT (G1_NK * G1_NT * 512)            // 138240
#define HS (HT + G2_NK * G2_NT * 512)       // 382464
#define H_TOTAL (HS + G3_NK * G3_NT * 512)  // 412160 halfwords = 824320 B

// ---------------- prep: build f16 B-fragment-packed weights in ws ----------------
// layout per region: [kstep][ntile][lane 0:64][j 0:8] ; value = W[k=kb*32+(lane>>4)*8+j][n=nt*16+(lane&15)]
__global__ __launch_bounds__(256) void ffm_prep(
    const float* __restrict__ au_, const float* __restrict__ ai_,
    const float* __restrict__ gu_, const float* __restrict__ gi_,
    const float* __restrict__ ou_, const float* __restrict__ oi_,
    const float* __restrict__ mu_, const float* __restrict__ mi_,
    const float* __restrict__ uu_, const float* __restrict__ ui_,
    const float* __restrict__ tu_, const float* __restrict__ ti_,
    const float* __restrict__ lw, _Float16* __restrict__ ws) {
  int e = blockIdx.x * 256 + threadIdx.x;
  if (e >= H_TOTAL) return;
  float val = 0.f;
  int rel, ntiles;
  if (e < HT) { rel = e; ntiles = G1_NT; }
  else if (e < HS) { rel = e - HT; ntiles = G2_NT; }
  else { rel = e - HS; ntiles = G3_NT; }
  int perk = ntiles * 512;
  int kb = rel / perk;
  int r = rel - kb * perk;
  int nt = r >> 9; r &= 511;
  int lane = r >> 3, j = r & 7;
  int k = kb * 32 + ((lane >> 4) << 3) + j;
  int n = (nt << 4) + (lane & 15);

  if (e < HT) {                               // G1: cols 0..959 (real < 943)
    if (k < 943) {
      if (n < 64) val = uu_[k * 64 + n];
      else if (n < 128) val = ui_[k * 64 + n - 64];
      else if (n == 128) val = lw[k];
    }
  } else if (e < HS) {                        // G2: cols 940..2635
    int col = 940 + k;
    if (n < 64) { if (col >= 943 && col < 2625) val = tu_[(col - 943) * 64 + n]; }
    else if (n < 128) { if (col >= 943 && col < 2625) val = ti_[(col - 943) * 64 + n - 64]; }
    else if (n == 128) { if (col >= 943 && col <= 2635) val = lw[col]; }
  } else {                                    // G3: cols 2624..2687 (real < 2668)
    int col = 2624 + k;
    if (n == 448) { if (col >= 2636 && col < 2668) val = lw[col]; }
    else if (n < 448) {
      int blk = n >> 6, d = n & 63;
      float ageu = (col == 2626) ? au_[d] : 0.f;
      float agei = (col == 2626) ? ai_[d] : 0.f;
      float genu = (col >= 2626 && col < 2628) ? gu_[(col - 2626) * 64 + d] : 0.f;
      float geni = (col >= 2626 && col < 2628) ? gi_[(col - 2626) * 64 + d] : 0.f;
      float occu = (col >= 2628 && col < 2649) ? ou_[(col - 2628) * 64 + d] : 0.f;
      float occi = (col >= 2628 && col < 2649) ? oi_[(col - 2628) * 64 + d] : 0.f;
      float movu = (col >= 2649 && col < 2668) ? mu_[(col - 2649) * 64 + d] : 0.f;
      float movi = (col >= 2649 && col < 2668) ? mi_[(col - 2649) * 64 + d] : 0.f;
      switch (blk) {
        case 0: val = ageu + genu + occu; break;  // P  = au+gu+ou
        case 1: val = agei + geni + occi; break;  // Q0 = ai+gi+oi
        case 2: val = movu; break;                // mu
        case 3: val = movi; break;                // mi
        case 4: val = ageu; break;                // au
        case 5: val = genu; break;                // gu
        case 6: val = occu; break;                // ou
      }
    }
  }
  ws[e] = (_Float16)val;
}

// ---------------- main kernel helpers ----------------
template <int NT>
__device__ __forceinline__ void stageB(const _Float16* __restrict__ src, char* lds,
                                       int bufOff, int tid, int wave) {
  constexpr int chunks = NT * 64;  // 16B chunks per kstep image
#pragma unroll
  for (int base = 0; base < chunks; base += 256) {
    int idx = base + tid;
    if (idx < chunks) {
      __builtin_amdgcn_global_load_lds(
          (const __attribute__((address_space(1))) void*)(src + (size_t)idx * 8),
          (__attribute__((address_space(3))) void*)(lds + bufOff + (base + wave * 64) * 16),
          16, 0, 0);
    }
  }
}

template <bool GUARD>
__device__ __forceinline__ void loadA(f32x4& a0, f32x4& a1,
                                      const float* __restrict__ myrow, int c0) {
  f32x4 z = {0.f, 0.f, 0.f, 0.f};
  if (!GUARD || (c0 + 4) <= FDIM) a0 = *(const f32x4*)(myrow + c0); else a0 = z;
  if (!GUARD || (c0 + 8) <= FDIM) a1 = *(const f32x4*)(myrow + c0 + 4); else a1 = z;
}

// One GEMM phase: M=16 rows/wave, N=NT*16, K=nk*32. A direct from global (fp32->f16),
// B double-buffered via global_load_lds from the prepacked image.
template <int NT, bool GUARD>
__device__ __forceinline__ void gemm_phase(const float* __restrict__ myrow, int colbase,
                                           int nk, const _Float16* __restrict__ wsrc,
                                           char* lds, int tid, int lane, int kg, int wave,
                                           f32x4* acc) {
  stageB<NT>(wsrc, lds, 0, tid, wave);
  f32x4 a0, a1;
  loadA<GUARD>(a0, a1, myrow, colbase + kg * 8);
  int cur = 0;
  for (int kb = 0; kb < nk; ++kb) {
    __syncthreads();  // buf[cur] staged; everyone done reading buf[cur^1]
    f32x4 n0 = {0.f, 0.f, 0.f, 0.f}, n1 = {0.f, 0.f, 0.f, 0.f};
    if (kb + 1 < nk) {
      stageB<NT>(wsrc + (size_t)(kb + 1) * (NT * 512), lds, (cur ^ 1) * BUF_BYTES, tid, wave);
      loadA<GUARD>(n0, n1, myrow, colbase + (kb + 1) * 32 + kg * 8);
    }
    f16x8 af;
#pragma unroll
    for (int i = 0; i < 4; ++i) { af[i] = (_Float16)a0[i]; af[4 + i] = (_Float16)a1[i]; }
    const char* buf = lds + cur * BUF_BYTES + lane * 16;
#pragma unroll
    for (int nt = 0; nt < NT; ++nt) {
      f16x8 bf = *(const f16x8*)(buf + nt * 1024);
      acc[nt] = __builtin_amdgcn_mfma_f32_16x16x32_f16(af, bf, acc[nt], 0, 0, 0);
    }
    a0 = n0; a1 = n1;
    cur ^= 1;
  }
}

// ---------------- main kernel ----------------
__global__ __launch_bounds__(256, 2) void ffm_main(
    const float* __restrict__ fv, const _Float16* __restrict__ wp,
    const float* __restrict__ linb, float* __restrict__ out) {
  __shared__ __align__(16) char lds[2 * BUF_BYTES];
  const int tid = threadIdx.x;
  const int lane = tid & 63;
  const int wave = tid >> 6;
  const int nl = lane & 15;
  const int kg = lane >> 4;
  const int rowbase = blockIdx.x * 64 + wave * 16;
  const float* myrow = fv + (size_t)(rowbase + nl) * FDIM;
  const f32x4 zero4 = {0.f, 0.f, 0.f, 0.f};

  // ---- G3: small fields -> P, Q0, mu, mi (+ au,gu,ou for the small-small cross, + lin)
  f32x4 s[G3_NT];
#pragma unroll
  for (int i = 0; i < G3_NT; ++i) s[i] = zero4;
  gemm_phase<G3_NT, true>(myrow, 2624, G3_NK, wp + HS, lds, tid, lane, kg, wave, s);

  f32x4 P[4], Q[4], MU[4], MI[4];
  f32x4 cross = s[28];  // lin partial (cols 2636..2667); nonzero only on nl==0
#pragma unroll
  for (int t = 0; t < 4; ++t) {
    P[t] = s[t]; Q[t] = s[4 + t]; MU[t] = s[8 + t]; MI[t] = s[12 + t];
    // smallcross = au·(gu+ou) + gu·ou + mu·Q0  (per-lane partial, reduced at the end)
    cross += s[16 + t] * (s[20 + t] + s[24 + t]) + s[20 + t] * s[24 + t] + MU[t] * Q[t];
  }

  // ---- G1: userid -> uu, ui
  f32x4 u[G1_NT];
#pragma unroll
  for (int i = 0; i < G1_NT; ++i) u[i] = zero4;
  gemm_phase<G1_NT, false>(myrow, 0, G1_NK, wp + HU, lds, tid, lane, kg, wave, u);
  cross += u[8];  // lin partial cols 0..942
#pragma unroll
  for (int t = 0; t < 4; ++t) {
    cross += u[t] * P[t] + u[4 + t] * MU[t];  // uu·P + ui·mu
    Q[t] += u[4 + t];                          // Q = Q0 + ui
  }

  // ---- G2: itemid -> tu, ti
  f32x4 v[G2_NT];
#pragma unroll
  for (int i = 0; i < G2_NT; ++i) v[i] = zero4;
  gemm_phase<G2_NT, false>(myrow, 940, G2_NK, wp + HT, lds, tid, lane, kg, wave, v);
  cross += v[8];  // lin partial cols 943..2635
#pragma unroll
  for (int t = 0; t < 4; ++t) {
    cross += v[t] * Q[t] + v[4 + t] * MI[t];  // tu·Q + ti·mi
  }

  // ---- reduce over the 16 lanes of each row-group (d dimension) and store
  float c0 = cross[0], c1 = cross[1], c2 = cross[2], c3 = cross[3];
#pragma unroll
  for (int m = 1; m <= 8; m <<= 1) {
    c0 += __shfl_xor(c0, m, 64);
    c1 += __shfl_xor(c1, m, 64);
    c2 += __shfl_xor(c2, m, 64);
    c3 += __shfl_xor(c3, m, 64);
  }
  if (nl == 0) {
    float lb = linb[0];
    int r = rowbase + kg * 4;
    out[r + 0] = 1.f / (1.f + __expf(-(c0 + lb)));
    out[r + 1] = 1.f / (1.f + __expf(-(c1 + lb)));
    out[r + 2] = 1.f / (1.f + __expf(-(c2 + lb)));
    out[r + 3] = 1.f / (1.f + __expf(-(c3 + lb)));
  }
}

extern "C" void kernel_launch(void* const* d_in, const int* in_sizes, int n_in,
                              void* d_out, int out_size, void* d_ws, size_t ws_size,
                              hipStream_t stream) {
  const float* fv    = (const float*)d_in[0];
  const float* age_u = (const float*)d_in[1];
  const float* age_i = (const float*)d_in[2];
  const float* gen_u = (const float*)d_in[3];
  const float* gen_i = (const float*)d_in[4];
  const float* occ_u = (const float*)d_in[5];
  const float* occ_i = (const float*)d_in[6];
  const float* mov_u = (const float*)d_in[7];
  const float* mov_i = (const float*)d_in[8];
  const float* uid_u = (const float*)d_in[9];
  const float* uid_i = (const float*)d_in[10];
  const float* iid_u = (const float*)d_in[11];
  const float* iid_i = (const float*)d_in[12];
  const float* lin_w = (const float*)d_in[13];
  const float* lin_b = (const float*)d_in[14];
  _Float16* ws = (_Float16*)d_ws;
  float* out = (float*)d_out;

  ffm_prep<<<(H_TOTAL + 255) / 256, 256, 0, stream>>>(
      age_u, age_i, gen_u, gen_i, occ_u, occ_i, mov_u, mov_i,
      uid_u, uid_i, iid_u, iid_i, lin_w, ws);
  ffm_main<<<32768 / 64, 256, 0, stream>>>(fv, ws, lin_b, out);
}